// Round 9
// baseline (1290.784 us; speedup 1.0000x reference)
//
#include <hip/hip_runtime.h>
#include <hip/hip_fp16.h>
#include <math.h>

// GCN 2-layer (DGL GraphConv norm='both'). TWO REGULAR launches (cooperative
// launch is poisoned in this harness: rounds 7/8 coop kernels ran 650-850us
// with 20x rocprof slowdowns; same bodies as plain launches run fine):
//   K1 histA_featw1: round-6 kernel verbatim (own compilation unit so the 64
//      named-VGPR W1 column can't be spilled by other phases' regalloc —
//      round-7 fusion proved that hazard). Also zeroes the global barrier.
//   K2 gcn_tail: PERSISTENT blocks (grid = CUs x occupancy, cap 1024, 2KB LDS,
//      launch_bounds(256,4) -> co-residency guaranteed) with a monotonic
//      software grid barrier (device-scope atomicAdd + acquire spin + s_sleep)
//      between phases: scan-sums -> scan-apply -> partition -> finalize ->
//      agg1 -> agg2. Replaces 6 launch boundaries (~10us each, rocprof.md).
// Requires N <= 65536 (src packed into 17 bits, NB <= 256). N=50000 here.

#define BS 256
#define EPB 2048    // edges per hist/partition chunk (8 iters of 256)
#define SCB 2048    // elements per scan chunk (256 thr x 8)

// ---- K1: per-block dst+src hists + featw1 (round-6 verbatim + bar zero) ----
__global__ __launch_bounds__(256, 4)
void histA_featw1_kernel(const int* __restrict__ src, const int* __restrict__ dst,
                         const float* __restrict__ feat, const float* __restrict__ W1,
                         int* __restrict__ dhist,
                         __half* __restrict__ featp, int* __restrict__ gbarCnt,
                         int E, int N, int NB, int T, int M) {
    __shared__ float4 ftile[64 * 16];   // 64 feat rows (16KB)
    __shared__ int histD[256];
    __shared__ int histS[256];
    int tid = threadIdx.x;
    if (blockIdx.x == 0 && tid == 0) *gbarCnt = 0;   // K2 barrier counter
    if ((int)blockIdx.x < T) {
        histD[tid] = 0; histS[tid] = 0;
        __syncthreads();
        int base = blockIdx.x * EPB;
        #pragma unroll
        for (int it = 0; it < EPB / BS; it++) {
            int e = base + it * BS + tid;
            if (e < E) {
                atomicAdd(&histD[dst[e] >> 8], 1);
                atomicAdd(&histS[src[e] >> 8], 1);
            }
        }
        __syncthreads();
        if (tid < NB) {
            dhist[tid * T + (int)blockIdx.x] = histD[tid];
            dhist[M + tid * T + (int)blockIdx.x] = histS[tid];
        }
    } else {
        int lane = tid & 63;
        int wave = tid >> 6;
        // W1 column for this lane: 64 named scalars (static -> registers).
        #define WD(i) float wv##i = W1[(i) * 64 + lane];
        WD(0)  WD(1)  WD(2)  WD(3)  WD(4)  WD(5)  WD(6)  WD(7)
        WD(8)  WD(9)  WD(10) WD(11) WD(12) WD(13) WD(14) WD(15)
        WD(16) WD(17) WD(18) WD(19) WD(20) WD(21) WD(22) WD(23)
        WD(24) WD(25) WD(26) WD(27) WD(28) WD(29) WD(30) WD(31)
        WD(32) WD(33) WD(34) WD(35) WD(36) WD(37) WD(38) WD(39)
        WD(40) WD(41) WD(42) WD(43) WD(44) WD(45) WD(46) WD(47)
        WD(48) WD(49) WD(50) WD(51) WD(52) WD(53) WD(54) WD(55)
        WD(56) WD(57) WD(58) WD(59) WD(60) WD(61) WD(62) WD(63)
        #undef WD
        // stage 64 feat rows into LDS (coalesced, 4 float4/thread)
        int rBase = ((int)blockIdx.x - T) * 64;
        const float4* feat4 = (const float4*)feat;
        int maxF4 = N * 16 - 1;
        #pragma unroll
        for (int it = 0; it < 4; it++) {
            int idx = it * BS + tid;
            ftile[idx] = feat4[min(rBase * 16 + idx, maxF4)];
        }
        __syncthreads();
        // 16 rows per wave; per row: 16 b128 broadcast reads + 64 FMA
        #pragma unroll 1
        for (int rr = 0; rr < 16; rr++) {
            int r = wave * 16 + rr;
            const float4* ft = &ftile[r * 16];
            float a0 = 0.0f, a1 = 0.0f, a2 = 0.0f, a3 = 0.0f;
            #define RK(k4, wA, wB, wC, wD_) { float4 f = ft[k4]; \
                a0 = fmaf(f.x, wA, a0); a1 = fmaf(f.y, wB, a1); \
                a2 = fmaf(f.z, wC, a2); a3 = fmaf(f.w, wD_, a3); }
            RK(0,  wv0,  wv1,  wv2,  wv3)  RK(1,  wv4,  wv5,  wv6,  wv7)
            RK(2,  wv8,  wv9,  wv10, wv11) RK(3,  wv12, wv13, wv14, wv15)
            RK(4,  wv16, wv17, wv18, wv19) RK(5,  wv20, wv21, wv22, wv23)
            RK(6,  wv24, wv25, wv26, wv27) RK(7,  wv28, wv29, wv30, wv31)
            RK(8,  wv32, wv33, wv34, wv35) RK(9,  wv36, wv37, wv38, wv39)
            RK(10, wv40, wv41, wv42, wv43) RK(11, wv44, wv45, wv46, wv47)
            RK(12, wv48, wv49, wv50, wv51) RK(13, wv52, wv53, wv54, wv55)
            RK(14, wv56, wv57, wv58, wv59) RK(15, wv60, wv61, wv62, wv63)
            #undef RK
            int rowg = rBase + r;
            if (rowg < N)
                featp[(size_t)rowg * 64 + lane] = __float2half((a0 + a1) + (a2 + a3));
        }
    }
}

// ---- software grid barrier: monotonic counter, device scope ----
__device__ __forceinline__ void grid_barrier(int* cnt, int gen) {
    __syncthreads();
    if (threadIdx.x == 0) {
        __threadfence();   // release: this block's writes visible device-wide
        __hip_atomic_fetch_add(cnt, 1, __ATOMIC_ACQ_REL, __HIP_MEMORY_SCOPE_AGENT);
        int target = (int)gridDim.x * gen;
        while (__hip_atomic_load(cnt, __ATOMIC_ACQUIRE, __HIP_MEMORY_SCOPE_AGENT) < target)
            __builtin_amdgcn_s_sleep(1);
    }
    __syncthreads();
    __threadfence();       // acquire: invalidate stale L1 before reading others' data
}

// ---- K2: persistent tail: scans -> partition -> finalize -> agg1 -> agg2 ----
__global__ __launch_bounds__(256, 4)
void gcn_tail_kernel(const int* __restrict__ src, const int* __restrict__ dst,
                     const float* __restrict__ b1, const float* __restrict__ W2,
                     const float* __restrict__ b2,
                     int* __restrict__ dhist, int* __restrict__ bsum,
                     int* __restrict__ in_deg, int* __restrict__ row_start,
                     int* __restrict__ out_deg, int* __restrict__ packed,
                     unsigned char* __restrict__ srcPartB, int* __restrict__ csr_src,
                     __half* __restrict__ featp, float* __restrict__ s_buf,
                     float* __restrict__ out, int* __restrict__ gbarCnt,
                     int E, int N, int NB, int T, int M, int NSB, int NA1, int NA2)
{
    __shared__ int shA[256];
    __shared__ int shB[256];
    const int tid = threadIdx.x;
    const int nblk = gridDim.x;
    const int M2 = 2 * M;

    // ---- P2: chunk sums -> bsum ----
    for (int vb = blockIdx.x; vb < NSB; vb += nblk) {
        int base = vb * SCB + tid * 8;
        int sum = 0;
        #pragma unroll
        for (int i = 0; i < 8; i++) { int k = base + i; if (k < M2) sum += dhist[k]; }
        shA[tid] = sum; __syncthreads();
        for (int off = 1; off < 256; off <<= 1) {
            int u = (tid >= off) ? shA[tid - off] : 0; __syncthreads();
            shA[tid] += u; __syncthreads();
        }
        if (tid == 255) bsum[vb] = shA[255];
        __syncthreads();
    }
    grid_barrier(gbarCnt, 1);

    // ---- P3: full exclusive scan of dhist in place (local bsum re-scan) ----
    for (int vb = blockIdx.x; vb < NSB; vb += nblk) {
        int v0 = (tid < NSB) ? bsum[tid] : 0;
        shA[tid] = v0; __syncthreads();
        for (int off = 1; off < 256; off <<= 1) {
            int u = (tid >= off) ? shA[tid - off] : 0; __syncthreads();
            shA[tid] += u; __syncthreads();
        }
        int blkBase = (vb > 0) ? shA[vb - 1] : 0;
        int base = vb * SCB + tid * 8;
        int v[8]; int sum = 0;
        #pragma unroll
        for (int i = 0; i < 8; i++) { int k = base + i; v[i] = (k < M2) ? dhist[k] : 0; sum += v[i]; }
        shB[tid] = sum; __syncthreads();
        for (int off = 1; off < 256; off <<= 1) {
            int u = (tid >= off) ? shB[tid - off] : 0; __syncthreads();
            shB[tid] += u; __syncthreads();
        }
        int run = blkBase + shB[tid] - sum;
        #pragma unroll
        for (int i = 0; i < 8; i++) { int k = base + i; if (k < M2) dhist[k] = run; run += v[i]; }
        __syncthreads();
    }
    grid_barrier(gbarCnt, 2);

    // ---- P4: partition (both scatters, one pass) ----
    for (int vb = blockIdx.x; vb < T; vb += nblk) {
        shA[tid] = (tid < NB) ? dhist[tid * T + vb] : 0;
        shB[tid] = (tid < NB) ? (dhist[M + tid * T + vb] - E) : 0;
        __syncthreads();
        int base = vb * EPB;
        #pragma unroll
        for (int it = 0; it < EPB / BS; it++) {
            int e = base + it * BS + tid;
            if (e < E) {
                int d = dst[e], s2 = src[e];
                int pos = atomicAdd(&shA[d >> 8], 1);
                packed[pos] = s2 | ((d & 255) << 17);
                int pos2 = atomicAdd(&shB[s2 >> 8], 1);
                srcPartB[pos2] = (unsigned char)(s2 & 255);
            }
        }
        __syncthreads();
    }
    grid_barrier(gbarCnt, 3);

    // ---- P5: finalize ----
    for (int vb = blockIdx.x; vb < 2 * NB; vb += nblk) {
        if (vb < NB) {
            int b = vb;
            int lo = dhist[b * T];
            int hi = (b + 1 < NB) ? dhist[(b + 1) * T] : E;
            shA[tid] = 0; __syncthreads();
            for (int i = lo + tid; i < hi; i += BS)
                atomicAdd(&shA[(packed[i] >> 17) & 255], 1);
            __syncthreads();
            int v = shA[tid];
            shB[tid] = v; __syncthreads();
            for (int off = 1; off < 256; off <<= 1) {
                int u = (tid >= off) ? shB[tid - off] : 0; __syncthreads();
                shB[tid] += u; __syncthreads();
            }
            int ex = shB[tid] - v;
            int n = b * 256 + tid;
            if (n < N) { in_deg[n] = v; row_start[n] = lo + ex; }
            shB[tid] = lo + ex;
            __syncthreads();
            for (int i = lo + tid; i < hi; i += BS) {
                int pv = packed[i];
                int pos = atomicAdd(&shB[(pv >> 17) & 255], 1);
                csr_src[pos] = pv & 0x1FFFF;
            }
            __syncthreads();
        } else {
            int sb = vb - NB;
            int lo = dhist[M + sb * T] - E;
            int hi = ((sb + 1 < NB) ? dhist[M + (sb + 1) * T] : 2 * E) - E;
            shA[tid] = 0; __syncthreads();
            for (int i = lo + tid; i < hi; i += BS)
                atomicAdd(&shA[srcPartB[i]], 1);
            __syncthreads();
            int n = sb * 256 + tid;
            int od = shA[tid];
            if (n < N) out_deg[n] = od;
            float* snorm = (float*)shB;
            snorm[tid] = rsqrtf(fmaxf((float)od, 1.0f));
            __syncthreads();
            int nodes = min(256, N - sb * 256);
            uint4* fp = (uint4*)(featp + (size_t)sb * 256 * 64);
            int total = nodes * 8;
            for (int i = tid; i < total; i += BS) {
                float s = snorm[i >> 3];
                uint4 u = fp[i];
                __half2* hh = (__half2*)&u;
                #pragma unroll
                for (int c = 0; c < 4; c++) {
                    float2 p = __half22float2(hh[c]);
                    p.x *= s; p.y *= s;
                    hh[c] = __float22half2_rn(p);
                }
                fp[i] = u;
            }
            __syncthreads();
        }
    }
    grid_barrier(gbarCnt, 4);

    // ---- P6: agg1 (one wave per node) ----
    for (int vb = blockIdx.x; vb < NA1; vb += nblk) {
        int n = vb * 4 + (tid >> 6);
        if (n < N) {
            int lane = tid & 63;
            int g = lane >> 3;
            int l = lane & 7;
            int start = row_start[n];
            int deg = in_deg[n];
            float acc[8] = {0, 0, 0, 0, 0, 0, 0, 0};
            const uint4* fp4 = (const uint4*)featp;
            for (int j = 0; j < deg; j += 16) {
                int e0 = j + g;
                int e1 = j + 8 + g;
                bool p0 = e0 < deg;
                bool p1 = e1 < deg;
                int sn0 = p0 ? csr_src[start + e0] : 0;
                int sn1 = p1 ? csr_src[start + e1] : 0;
                uint4 q0 = {0, 0, 0, 0}, q1 = {0, 0, 0, 0};
                if (p0) q0 = fp4[(size_t)sn0 * 8 + l];
                if (p1) q1 = fp4[(size_t)sn1 * 8 + l];
                const __half2* h0 = (const __half2*)&q0;
                const __half2* h1 = (const __half2*)&q1;
                #pragma unroll
                for (int c = 0; c < 4; c++) {
                    float2 f0 = __half22float2(h0[c]);
                    float2 f1 = __half22float2(h1[c]);
                    acc[2 * c]     += f0.x + f1.x;
                    acc[2 * c + 1] += f0.y + f1.y;
                }
            }
            #pragma unroll
            for (int off = 8; off < 64; off <<= 1) {
                #pragma unroll
                for (int c = 0; c < 8; c++)
                    acc[c] += __shfl_xor(acc[c], off, 64);
            }
            float inn = rsqrtf(fmaxf((float)deg, 1.0f));
            float v = 0.0f;
            #pragma unroll
            for (int c = 0; c < 8; c++) {
                float h = fmaxf(inn * acc[c] + b1[l * 8 + c], 0.0f);
                v += h * W2[l * 8 + c];
            }
            #pragma unroll
            for (int off = 1; off < 8; off <<= 1)
                v += __shfl_xor(v, off, 64);
            if (lane == 0)
                s_buf[n] = rsqrtf(fmaxf((float)out_deg[n], 1.0f)) * v;
        }
    }
    grid_barrier(gbarCnt, 5);

    // ---- P7: agg2 (16 lanes per node) ----
    for (int vb = blockIdx.x; vb < NA2; vb += nblk) {
        int n = vb * 16 + (tid >> 4);
        if (n < N) {
            int sub = tid & 15;
            int start = row_start[n];
            int deg = in_deg[n];
            float a = 0.0f;
            for (int j = sub; j < deg; j += 32) {
                int j1 = j + 16;
                int i0 = csr_src[start + j];
                int i1 = (j1 < deg) ? csr_src[start + j1] : 0;
                float v0 = s_buf[i0];
                float v1 = (j1 < deg) ? s_buf[i1] : 0.0f;
                a += v0 + v1;
            }
            #pragma unroll
            for (int off = 1; off < 16; off <<= 1)
                a += __shfl_xor(a, off, 64);
            if (sub == 0) {
                float x = rsqrtf(fmaxf((float)deg, 1.0f)) * a + b2[0];
                out[n] = 1.0f / (1.0f + expf(-x));
            }
        }
    }
}

extern "C" void kernel_launch(void* const* d_in, const int* in_sizes, int n_in,
                              void* d_out, int out_size, void* d_ws, size_t ws_size,
                              hipStream_t stream) {
    const float* feat = (const float*)d_in[0];
    const float* W1   = (const float*)d_in[1];
    const float* b1   = (const float*)d_in[2];
    const float* W2   = (const float*)d_in[3];
    const float* b2   = (const float*)d_in[4];
    const int* src = (const int*)d_in[5];
    const int* dst = (const int*)d_in[6];
    float* out = (float*)d_out;

    int N  = in_sizes[0] / 64;       // 50000
    int E  = in_sizes[5];            // 800000
    int NB = (N + 255) >> 8;         // 196 bins of 256 nodes
    int T  = (E + EPB - 1) / EPB;    // 391 hist/partition chunks
    int M  = NB * T;                 // per-side flat (bin, chunk) counts
    int M2 = 2 * M;
    int NSB = (M2 + SCB - 1) / SCB;  // 75 scan chunks (<=256 required by P3)
    int NA1 = (N + 3) / 4;           // agg1 chunks (4 nodes each)
    int NA2 = (N + 15) / 16;         // agg2 chunks (16 nodes each)

    // workspace: int region | srcPart bytes | fp16 featp (16B-aligned) | float s_buf
    int* wsi = (int*)d_ws;
    int* bsum        = wsi;                          // NSB
    int* gbarCnt     = bsum + NSB;                   // 1 (zeroed by K1)
    int* in_deg      = gbarCnt + 1;                  // N
    int* row_start   = in_deg + N;                   // N
    int* out_deg     = row_start + N;                // N (fully written in P5)
    int* dhist       = out_deg + N;                  // 2*M (fully overwritten)
    int* packed      = dhist + M2;                   // E
    int* csr_src     = packed + E;                   // E
    unsigned char* srcPartB = (unsigned char*)(csr_src + E);      // E bytes
    size_t int_bytes = ((size_t)NSB + 1 + 3 * (size_t)N + (size_t)M2 + 2 * (size_t)E) * sizeof(int)
                     + (size_t)E;
    size_t half_off  = (int_bytes + 15) & ~(size_t)15;
    __half* featp = (__half*)((char*)d_ws + half_off);            // 64N fp16
    float* s_buf  = (float*)((char*)d_ws + half_off + (size_t)64 * N * sizeof(__half));

    // K1: hist + featw1 (regular launch; zeroes gbarCnt before K2 starts)
    histA_featw1_kernel<<<T + (N + 63) / 64, BS, 0, stream>>>(
        src, dst, feat, W1, dhist, featp, gbarCnt, E, N, NB, T, M);

    // K2: persistent blocks; grid = min(CUs x occupancy, 1024) -> co-resident
    static int gridBlocks = 0;
    if (gridBlocks == 0) {
        int mb = 0;
        hipOccupancyMaxActiveBlocksPerMultiprocessor(&mb, gcn_tail_kernel, BS, 0);
        if (mb < 1) mb = 1;
        int dev = 0;
        hipGetDevice(&dev);
        hipDeviceProp_t prop;
        int cus = 256;
        if (hipGetDeviceProperties(&prop, dev) == hipSuccess && prop.multiProcessorCount > 0)
            cus = prop.multiProcessorCount;
        long g = (long)cus * mb;
        gridBlocks = (int)((g > 1024) ? 1024 : g);
    }

    gcn_tail_kernel<<<gridBlocks, BS, 0, stream>>>(
        src, dst, b1, W2, b2, dhist, bsum, in_deg, row_start, out_deg,
        packed, srcPartB, csr_src, featp, s_buf, out, gbarCnt,
        E, N, NB, T, M, NSB, NA1, NA2);
}

// Round 10
// 206.724 us; speedup vs baseline: 6.2440x; 6.2440x over previous
//
#include <hip/hip_runtime.h>
#include <hip/hip_fp16.h>
#include <math.h>

// GCN 2-layer (DGL GraphConv norm='both'). FIVE regular launches (coop launch
// and persistent+SW-barrier fusion both proven pathological: r7/r8 coop =
// harness 20x slowdown; r9 SW barrier = 240us/barrier single-line atomic
// serialization across XCDs). Launch-count minimized instead:
//   K1 histA_featw1: per-block LDS hists of dst>>8 / src>>8 -> dhist[bin*T+b]
//      (+ global binCount atomicAdds, 38k tiny) co-scheduled with featw1 =
//      fp16(feat @ W1), W1 column in 64 NAMED VGPRs (own compilation unit --
//      r7 proved co-compiled phases spill it). LAST-BLOCK-DONE epilogue
//      (threadfence+atomicAdd(doneCnt)) scans the 2x196 bin counts -> bases
//      + cursors, replacing a separate scan launch. NO flat dhist scan at all:
//      partition reserves ranges with global cursor atomics (round-0-proven).
//   K2 partition: block b loads its own counts from dhist, reserves
//      rb=atomicAdd(cursor[bin],h), scatters packed (src|dstLow<<17) and
//      src-low bytes in ONE pass. Within-bin edge order is chunk-arbitrary --
//      harmless (per-node sums order-insensitive; round 0 passed identically).
//   K3 finalize: dst bins -> in_deg/row_start/csr_src; src bins -> out_deg +
//      featp *= rsqrt(out_deg) (keeps per-edge out_norm out of agg1).
//   K4 agg1: one wave/node, 8 edge-groups x 8 fp16 chunks; relu+b1+.W2 -> s_buf
//   K5 agg2: 16 lanes/node -> sigmoid -> out
// Requires N <= 65536 (src packed into 17 bits, NB <= 256). N=50000 here.

#define BS 256
#define EPB 2048    // edges per hist/partition chunk (8 iters of 256)

// ---- K1: per-block dst+src hists + featw1 + last-block bin scan ----
__global__ __launch_bounds__(256, 4)
void histA_featw1_kernel(const int* __restrict__ src, const int* __restrict__ dst,
                         const float* __restrict__ feat, const float* __restrict__ W1,
                         int* __restrict__ dhist,
                         int* __restrict__ binCountD, int* __restrict__ binCountS,
                         int* __restrict__ doneCnt,
                         int* __restrict__ dstBinBase, int* __restrict__ srcBinBase,
                         int* __restrict__ dstCursor, int* __restrict__ srcCursor,
                         __half* __restrict__ featp,
                         int E, int N, int NB, int T, int M) {
    __shared__ float4 ftile[64 * 16];   // 64 feat rows (16KB)
    __shared__ int histD[256];
    __shared__ int histS[256];
    __shared__ int isLast;
    int tid = threadIdx.x;
    if ((int)blockIdx.x < T) {
        histD[tid] = 0; histS[tid] = 0;
        __syncthreads();
        int base = blockIdx.x * EPB;
        #pragma unroll
        for (int it = 0; it < EPB / BS; it++) {
            int e = base + it * BS + tid;
            if (e < E) {
                atomicAdd(&histD[dst[e] >> 8], 1);
                atomicAdd(&histS[src[e] >> 8], 1);
            }
        }
        __syncthreads();
        if (tid < NB) {
            int hd = histD[tid], hs = histS[tid];
            dhist[tid * T + (int)blockIdx.x] = hd;
            dhist[M + tid * T + (int)blockIdx.x] = hs;
            if (hd) atomicAdd(&binCountD[tid], hd);
            if (hs) atomicAdd(&binCountS[tid], hs);
        }
    } else {
        int lane = tid & 63;
        int wave = tid >> 6;
        // W1 column for this lane: 64 named scalars (static -> registers).
        #define WD(i) float wv##i = W1[(i) * 64 + lane];
        WD(0)  WD(1)  WD(2)  WD(3)  WD(4)  WD(5)  WD(6)  WD(7)
        WD(8)  WD(9)  WD(10) WD(11) WD(12) WD(13) WD(14) WD(15)
        WD(16) WD(17) WD(18) WD(19) WD(20) WD(21) WD(22) WD(23)
        WD(24) WD(25) WD(26) WD(27) WD(28) WD(29) WD(30) WD(31)
        WD(32) WD(33) WD(34) WD(35) WD(36) WD(37) WD(38) WD(39)
        WD(40) WD(41) WD(42) WD(43) WD(44) WD(45) WD(46) WD(47)
        WD(48) WD(49) WD(50) WD(51) WD(52) WD(53) WD(54) WD(55)
        WD(56) WD(57) WD(58) WD(59) WD(60) WD(61) WD(62) WD(63)
        #undef WD
        // stage 64 feat rows into LDS (coalesced, 4 float4/thread)
        int rBase = ((int)blockIdx.x - T) * 64;
        const float4* feat4 = (const float4*)feat;
        int maxF4 = N * 16 - 1;
        #pragma unroll
        for (int it = 0; it < 4; it++) {
            int idx = it * BS + tid;
            ftile[idx] = feat4[min(rBase * 16 + idx, maxF4)];
        }
        __syncthreads();
        // 16 rows per wave; per row: 16 b128 broadcast reads + 64 FMA
        #pragma unroll 1
        for (int rr = 0; rr < 16; rr++) {
            int r = wave * 16 + rr;
            const float4* ft = &ftile[r * 16];
            float a0 = 0.0f, a1 = 0.0f, a2 = 0.0f, a3 = 0.0f;
            #define RK(k4, wA, wB, wC, wD_) { float4 f = ft[k4]; \
                a0 = fmaf(f.x, wA, a0); a1 = fmaf(f.y, wB, a1); \
                a2 = fmaf(f.z, wC, a2); a3 = fmaf(f.w, wD_, a3); }
            RK(0,  wv0,  wv1,  wv2,  wv3)  RK(1,  wv4,  wv5,  wv6,  wv7)
            RK(2,  wv8,  wv9,  wv10, wv11) RK(3,  wv12, wv13, wv14, wv15)
            RK(4,  wv16, wv17, wv18, wv19) RK(5,  wv20, wv21, wv22, wv23)
            RK(6,  wv24, wv25, wv26, wv27) RK(7,  wv28, wv29, wv30, wv31)
            RK(8,  wv32, wv33, wv34, wv35) RK(9,  wv36, wv37, wv38, wv39)
            RK(10, wv40, wv41, wv42, wv43) RK(11, wv44, wv45, wv46, wv47)
            RK(12, wv48, wv49, wv50, wv51) RK(13, wv52, wv53, wv54, wv55)
            RK(14, wv56, wv57, wv58, wv59) RK(15, wv60, wv61, wv62, wv63)
            #undef RK
            int rowg = rBase + r;
            if (rowg < N)
                featp[(size_t)rowg * 64 + lane] = __float2half((a0 + a1) + (a2 + a3));
        }
    }
    // ---- last-block-done epilogue: scan 2x196 bin counts (replaces a launch) ----
    __syncthreads();
    if (tid == 0) {
        __threadfence();
        int old = atomicAdd(doneCnt, 1);
        isLast = (old == (int)gridDim.x - 1) ? 1 : 0;
    }
    __syncthreads();
    if (isLast) {
        __threadfence();
        int v = (tid < NB) ? binCountD[tid] : 0;
        histD[tid] = v; __syncthreads();
        for (int off = 1; off < 256; off <<= 1) {
            int u = (tid >= off) ? histD[tid - off] : 0; __syncthreads();
            histD[tid] += u; __syncthreads();
        }
        if (tid < NB) {
            int ex = histD[tid] - v;
            dstBinBase[tid] = ex; dstCursor[tid] = ex;
            if (tid == NB - 1) dstBinBase[NB] = histD[tid];
        }
        __syncthreads();
        v = (tid < NB) ? binCountS[tid] : 0;
        histD[tid] = v; __syncthreads();
        for (int off = 1; off < 256; off <<= 1) {
            int u = (tid >= off) ? histD[tid - off] : 0; __syncthreads();
            histD[tid] += u; __syncthreads();
        }
        if (tid < NB) {
            int ex = histD[tid] - v;
            srcBinBase[tid] = ex; srcCursor[tid] = ex;
            if (tid == NB - 1) srcBinBase[NB] = histD[tid];
        }
    }
}

// ---- K2: partition: reserve ranges via cursor atomics, scatter both sides ----
__global__ void partition_kernel(const int* __restrict__ src, const int* __restrict__ dst,
                                 const int* __restrict__ dhist,
                                 int* __restrict__ dstCursor, int* __restrict__ srcCursor,
                                 int* __restrict__ packed, unsigned char* __restrict__ srcPartB,
                                 int E, int NB, int T, int M) {
    __shared__ int darr[256];
    __shared__ int sarr[256];
    int tid = threadIdx.x;
    int b = blockIdx.x;
    int hd = (tid < NB) ? dhist[tid * T + b] : 0;
    int hs = (tid < NB) ? dhist[M + tid * T + b] : 0;
    darr[tid] = (hd > 0) ? atomicAdd(&dstCursor[tid], hd) : 0;
    sarr[tid] = (hs > 0) ? atomicAdd(&srcCursor[tid], hs) : 0;
    __syncthreads();
    int base = b * EPB;
    #pragma unroll
    for (int it = 0; it < EPB / BS; it++) {
        int e = base + it * BS + tid;
        if (e < E) {
            int d = dst[e], s2 = src[e];
            int pos = atomicAdd(&darr[d >> 8], 1);
            packed[pos] = s2 | ((d & 255) << 17);
            int pos2 = atomicAdd(&sarr[s2 >> 8], 1);
            srcPartB[pos2] = (unsigned char)(s2 & 255);
        }
    }
}

// ---- K3: finalize: dst bins -> CSR; src bins -> out_deg + featp rescale ----
__global__ void finalize_kernel(const int* __restrict__ dstBinBase, const int* __restrict__ srcBinBase,
                                const int* __restrict__ packed,
                                const unsigned char* __restrict__ srcPartB,
                                int* __restrict__ csr_src, int* __restrict__ in_deg,
                                int* __restrict__ row_start, int* __restrict__ out_deg,
                                __half* __restrict__ featp,
                                int N, int NB) {
    __shared__ int hist[256];
    __shared__ int sc[256];
    int tid = threadIdx.x;
    int b = blockIdx.x;
    if (b < NB) {
        int lo = dstBinBase[b], hi = dstBinBase[b + 1];
        hist[tid] = 0; __syncthreads();
        for (int i = lo + tid; i < hi; i += BS)
            atomicAdd(&hist[(packed[i] >> 17) & 255], 1);
        __syncthreads();
        int v = hist[tid];
        sc[tid] = v; __syncthreads();
        for (int off = 1; off < 256; off <<= 1) {
            int u = (tid >= off) ? sc[tid - off] : 0; __syncthreads();
            sc[tid] += u; __syncthreads();
        }
        int ex = sc[tid] - v;          // exclusive within bin
        int n = b * 256 + tid;
        if (n < N) { in_deg[n] = v; row_start[n] = lo + ex; }
        sc[tid] = lo + ex;             // becomes the scatter cursor
        __syncthreads();
        for (int i = lo + tid; i < hi; i += BS) {
            int pv = packed[i];
            int pos = atomicAdd(&sc[(pv >> 17) & 255], 1);
            csr_src[pos] = pv & 0x1FFFF;
        }
    } else {
        int sb = b - NB;
        int lo = srcBinBase[sb], hi = srcBinBase[sb + 1];
        hist[tid] = 0; __syncthreads();
        for (int i = lo + tid; i < hi; i += BS)
            atomicAdd(&hist[srcPartB[i]], 1);
        __syncthreads();
        int n = sb * 256 + tid;
        int od = hist[tid];
        if (n < N) out_deg[n] = od;
        float* snorm = (float*)sc;     // reuse LDS
        snorm[tid] = rsqrtf(fmaxf((float)od, 1.0f));
        __syncthreads();
        // pre-scale featp rows of this bin by out_norm (contiguous 32KB block)
        int nodes = min(256, N - sb * 256);
        uint4* fp = (uint4*)(featp + (size_t)sb * 256 * 64);   // 8 uint4 per row
        int total = nodes * 8;
        for (int i = tid; i < total; i += BS) {
            float s = snorm[i >> 3];   // 8 lanes share a node -> LDS broadcast
            uint4 u = fp[i];
            __half2* hh = (__half2*)&u;
            #pragma unroll
            for (int c = 0; c < 4; c++) {
                float2 p = __half22float2(hh[c]);
                p.x *= s; p.y *= s;
                hh[c] = __float22half2_rn(p);
            }
            fp[i] = u;
        }
    }
}

// ---- K4: agg1: one wave/node; 8 edge-groups x 8 chunks; featp pre-scaled ----
__global__ void csr_agg1_kernel(const int* __restrict__ row_start, const int* __restrict__ in_deg,
                                const int* __restrict__ csr_src, const int* __restrict__ out_deg,
                                const __half* __restrict__ featp,
                                const float* __restrict__ b1, const float* __restrict__ W2,
                                float* __restrict__ s_buf, int N) {
    int gid = blockIdx.x * blockDim.x + threadIdx.x;
    int n = gid >> 6;
    if (n >= N) return;
    int lane = threadIdx.x & 63;
    int g = lane >> 3;   // edge slot within batch of 8
    int l = lane & 7;    // feature chunk: features [8l, 8l+8)
    int start = row_start[n];
    int deg = in_deg[n];
    float acc[8] = {0, 0, 0, 0, 0, 0, 0, 0};
    const uint4* fp4 = (const uint4*)featp;
    for (int j = 0; j < deg; j += 16) {
        int e0 = j + g;
        int e1 = j + 8 + g;
        bool p0 = e0 < deg;
        bool p1 = e1 < deg;
        int sn0 = p0 ? csr_src[start + e0] : 0;
        int sn1 = p1 ? csr_src[start + e1] : 0;
        uint4 q0 = {0, 0, 0, 0}, q1 = {0, 0, 0, 0};
        if (p0) q0 = fp4[(size_t)sn0 * 8 + l];
        if (p1) q1 = fp4[(size_t)sn1 * 8 + l];
        const __half2* h0 = (const __half2*)&q0;
        const __half2* h1 = (const __half2*)&q1;
        #pragma unroll
        for (int c = 0; c < 4; c++) {
            float2 f0 = __half22float2(h0[c]);
            float2 f1 = __half22float2(h1[c]);
            acc[2 * c]     += f0.x + f1.x;
            acc[2 * c + 1] += f0.y + f1.y;
        }
    }
    #pragma unroll
    for (int off = 8; off < 64; off <<= 1) {
        #pragma unroll
        for (int c = 0; c < 8; c++)
            acc[c] += __shfl_xor(acc[c], off, 64);
    }
    float inn = rsqrtf(fmaxf((float)deg, 1.0f));
    float v = 0.0f;
    #pragma unroll
    for (int c = 0; c < 8; c++) {
        float h = fmaxf(inn * acc[c] + b1[l * 8 + c], 0.0f);
        v += h * W2[l * 8 + c];
    }
    #pragma unroll
    for (int off = 1; off < 8; off <<= 1)
        v += __shfl_xor(v, off, 64);
    if (lane == 0)
        s_buf[n] = rsqrtf(fmaxf((float)out_deg[n], 1.0f)) * v;
}

// ---- K5: agg2: 16 lanes/node, unroll-2, sigmoid -> out ----
__global__ void csr_agg2_kernel(const int* __restrict__ row_start, const int* __restrict__ in_deg,
                                const int* __restrict__ csr_src,
                                const float* __restrict__ s_buf, const float* __restrict__ b2,
                                float* __restrict__ out, int N) {
    int gid = blockIdx.x * blockDim.x + threadIdx.x;
    int n = gid >> 4;
    if (n >= N) return;
    int sub = gid & 15;
    int start = row_start[n];
    int deg = in_deg[n];
    float a = 0.0f;
    for (int j = sub; j < deg; j += 32) {
        int j1 = j + 16;
        int i0 = csr_src[start + j];
        int i1 = (j1 < deg) ? csr_src[start + j1] : 0;
        float v0 = s_buf[i0];
        float v1 = (j1 < deg) ? s_buf[i1] : 0.0f;
        a += v0 + v1;
    }
    #pragma unroll
    for (int off = 1; off < 16; off <<= 1)
        a += __shfl_xor(a, off, 64);
    if (sub == 0) {
        float x = rsqrtf(fmaxf((float)deg, 1.0f)) * a + b2[0];
        out[n] = 1.0f / (1.0f + expf(-x));
    }
}

extern "C" void kernel_launch(void* const* d_in, const int* in_sizes, int n_in,
                              void* d_out, int out_size, void* d_ws, size_t ws_size,
                              hipStream_t stream) {
    const float* feat = (const float*)d_in[0];
    const float* W1   = (const float*)d_in[1];
    const float* b1   = (const float*)d_in[2];
    const float* W2   = (const float*)d_in[3];
    const float* b2   = (const float*)d_in[4];
    const int* src = (const int*)d_in[5];
    const int* dst = (const int*)d_in[6];
    float* out = (float*)d_out;

    int N  = in_sizes[0] / 64;       // 50000
    int E  = in_sizes[5];            // 800000
    int NB = (N + 255) >> 8;         // 196 bins of 256 nodes
    int T  = (E + EPB - 1) / EPB;    // 391 hist/partition chunks
    int M  = NB * T;                 // per-side flat (bin, chunk) counts

    // workspace: zeroed header | bases/cursors | per-node | dhist | edge arrays
    int* wsi = (int*)d_ws;
    int* binCountD   = wsi;                          // NB   (memset 0)
    int* binCountS   = binCountD + NB;               // NB   (memset 0)
    int* doneCnt     = binCountS + NB;               // 1    (memset 0)
    int* dstBinBase  = doneCnt + 1;                  // NB+1 (written by K1 epilogue)
    int* srcBinBase  = dstBinBase + NB + 1;          // NB+1
    int* dstCursor   = srcBinBase + NB + 1;          // NB
    int* srcCursor   = dstCursor + NB;               // NB
    int* in_deg      = srcCursor + NB;               // N
    int* row_start   = in_deg + N;                   // N
    int* out_deg     = row_start + N;                // N
    int* dhist       = out_deg + N;                  // 2*M (fully overwritten)
    int* packed      = dhist + 2 * M;                // E
    int* csr_src     = packed + E;                   // E
    unsigned char* srcPartB = (unsigned char*)(csr_src + E);      // E bytes
    size_t int_bytes = ((size_t)(6 * NB + 3) + 3 * (size_t)N + 2 * (size_t)M + 2 * (size_t)E) * sizeof(int)
                     + (size_t)E;
    size_t half_off  = (int_bytes + 15) & ~(size_t)15;
    __half* featp = (__half*)((char*)d_ws + half_off);            // 64N fp16
    float* s_buf  = (float*)((char*)d_ws + half_off + (size_t)64 * N * sizeof(__half));

    hipMemsetAsync(binCountD, 0, (size_t)(2 * NB + 1) * sizeof(int), stream);

    histA_featw1_kernel<<<T + (N + 63) / 64, BS, 0, stream>>>(
        src, dst, feat, W1, dhist, binCountD, binCountS, doneCnt,
        dstBinBase, srcBinBase, dstCursor, srcCursor, featp, E, N, NB, T, M);
    partition_kernel<<<T, BS, 0, stream>>>(
        src, dst, dhist, dstCursor, srcCursor, packed, srcPartB, E, NB, T, M);
    finalize_kernel<<<2 * NB, BS, 0, stream>>>(
        dstBinBase, srcBinBase, packed, srcPartB, csr_src, in_deg, row_start,
        out_deg, featp, N, NB);
    csr_agg1_kernel<<<(int)(((size_t)N * 64 + BS - 1) / BS), BS, 0, stream>>>(
        row_start, in_deg, csr_src, out_deg, featp, b1, W2, s_buf, N);
    csr_agg2_kernel<<<(int)(((size_t)N * 16 + BS - 1) / BS), BS, 0, stream>>>(
        row_start, in_deg, csr_src, s_buf, b2, out, N);
}